// Round 2
// baseline (214.671 us; speedup 1.0000x reference)
//
#include <hip/hip_runtime.h>

#define B_ 32
#define N_ 4096
#define C_ 16
#define D_ 256
#define NSPLIT 64
#define ROWS (N_ / NSPLIT)   // 64 rows per block
#define RPW  (ROWS / 4)      // 16 rows per wave

// One wave processes one full row (D=256 = 64 lanes x float4), two rows per
// iteration with a prefetched pair (up to 4 VMEM loads in flight / wave).
// Mask bits are wave-uniform (SGPR ballot) -> scalar branches, no divergence.
__global__ __launch_bounds__(256, 4)
void tensor_fusion_kernel(const float* __restrict__ r,
                          const float* __restrict__ v,
                          float* __restrict__ out) {
    const int b     = blockIdx.x >> 6;           // / NSPLIT
    const int chunk = blockIdx.x & (NSPLIT - 1);
    const int tid   = threadIdx.x;
    const int wave  = tid >> 6;
    const int lane  = tid & 63;
    const int d4    = lane << 2;

    const float* __restrict__ rb = r + (size_t)b * N_ * C_;
    const float* __restrict__ vp = v + (size_t)b * N_ * D_;
    const float scale = 1.0f / (float)N_;
    float* __restrict__ ob = out + (size_t)b * 17 * D_;

    float4 acc[16];
#pragma unroll
    for (int c = 0; c < 16; ++c) acc[c] = make_float4(0.f, 0.f, 0.f, 0.f);

    const int base = chunk * ROWS + wave * RPW;   // 16 consecutive rows / wave

    // ---- software pipeline: current pair (rv, va, vb4), prefetch next pair
    // lanes 0..31 hold r for rows (n, n+1): 128 B contiguous load, one ballot
    float  rv  = (lane < 32) ? rb[(size_t)base * C_ + lane] : 0.0f;
    float4 va  = *(const float4*)(vp + (size_t)base * D_ + d4);
    float4 vb4 = *(const float4*)(vp + (size_t)(base + 1) * D_ + d4);

    for (int i = 0; i < RPW; i += 2) {
        const int nn = base + ((i + 2 < RPW) ? i + 2 : i);  // clamp last pf
        const float  rv_n = (lane < 32) ? rb[(size_t)nn * C_ + lane] : 0.0f;
        const float4 va_n = *(const float4*)(vp + (size_t)nn * D_ + d4);
        const float4 vb_n = *(const float4*)(vp + (size_t)(nn + 1) * D_ + d4);

        const unsigned bal   = (unsigned)__ballot(rv >= 0.5f);
        const unsigned maskA = bal & 0xFFFFu;
        const unsigned maskB = (bal >> 16) & 0xFFFFu;
#pragma unroll
        for (int c = 0; c < 16; ++c) {
            if (maskA & (1u << c)) {           // wave-uniform scalar branch
                acc[c].x += va.x; acc[c].y += va.y;
                acc[c].z += va.z; acc[c].w += va.w;
            }
        }
#pragma unroll
        for (int c = 0; c < 16; ++c) {
            if (maskB & (1u << c)) {
                acc[c].x += vb4.x; acc[c].y += vb4.y;
                acc[c].z += vb4.z; acc[c].w += vb4.w;
            }
        }
        // "all categories below" row: prob 0.5^16 ~ 1.5e-5 -> rare direct atomic
        if (maskA == 0u) {
            atomicAdd(&ob[16 * D_ + d4 + 0], va.x * scale);
            atomicAdd(&ob[16 * D_ + d4 + 1], va.y * scale);
            atomicAdd(&ob[16 * D_ + d4 + 2], va.z * scale);
            atomicAdd(&ob[16 * D_ + d4 + 3], va.w * scale);
        }
        if (maskB == 0u) {
            atomicAdd(&ob[16 * D_ + d4 + 0], vb4.x * scale);
            atomicAdd(&ob[16 * D_ + d4 + 1], vb4.y * scale);
            atomicAdd(&ob[16 * D_ + d4 + 2], vb4.z * scale);
            atomicAdd(&ob[16 * D_ + d4 + 3], vb4.w * scale);
        }
        rv = rv_n; va = va_n; vb4 = vb_n;
    }

    // ---- cross-wave reduction in LDS (wave0 stores, waves 1..3 accumulate)
    __shared__ float4 lds4[16 * 64];    // 16 KiB
    if (wave == 0) {
#pragma unroll
        for (int c = 0; c < 16; ++c) lds4[c * 64 + lane] = acc[c];
    }
    __syncthreads();
    for (int w = 1; w < 4; ++w) {
        if (wave == w) {
#pragma unroll
            for (int c = 0; c < 16; ++c) {
                float4 t = lds4[c * 64 + lane];
                t.x += acc[c].x; t.y += acc[c].y;
                t.z += acc[c].z; t.w += acc[c].w;
                lds4[c * 64 + lane] = t;
            }
        }
        __syncthreads();
    }

    // ---- one coalesced atomicAdd stream per block (64 contributors/address)
    const float* lf = (const float*)lds4;
#pragma unroll
    for (int c = 0; c < 16; ++c) {
        atomicAdd(&ob[c * D_ + tid], lf[c * 256 + tid] * scale);
    }
}

extern "C" void kernel_launch(void* const* d_in, const int* in_sizes, int n_in,
                              void* d_out, int out_size, void* d_ws, size_t ws_size,
                              hipStream_t stream) {
    const float* r = (const float*)d_in[0];   // (B,N,C) fp32
    const float* v = (const float*)d_in[1];   // (B,N,D) fp32
    float* out = (float*)d_out;               // (B,C+1,D) fp32

    // harness re-poisons d_out to 0xAA before every timed launch
    hipMemsetAsync(out, 0, (size_t)out_size * sizeof(float), stream);

    dim3 grid(B_ * NSPLIT);
    tensor_fusion_kernel<<<grid, 256, 0, stream>>>(r, v, out);
}

// Round 3
// 203.449 us; speedup vs baseline: 1.0552x; 1.0552x over previous
//
#include <hip/hip_runtime.h>

#define B_ 32
#define N_ 4096
#define C_ 16
#define D_ 256
#define NSPLIT 64
#define ROWS (N_ / NSPLIT)   // 64 rows per block
#define RPW  (ROWS / 4)      // 16 rows per wave
#define NG   (RPW / 4)       // 4 groups of 4 rows per wave

// One wave = one full row of D (64 lanes x float4). Rows processed in groups
// of 4: a single 64-lane r-load covers 4 rows x 16 cats -> one ballot per
// group. Accumulation is mask-FMA: acc[c] += v * m_c with m_c in {0,1}
// derived from the wave-uniform ballot (scalar s_cselect, no branches, no
// per-element cndmask). Next group (1 r-load + 4 KB of v) prefetched while
// current group computes.
__global__ __launch_bounds__(256, 4)
void tensor_fusion_kernel(const float* __restrict__ r,
                          const float* __restrict__ v,
                          float* __restrict__ out) {
    const int b     = blockIdx.x >> 6;           // / NSPLIT
    const int chunk = blockIdx.x & (NSPLIT - 1);
    const int tid   = threadIdx.x;
    const int wave  = tid >> 6;
    const int lane  = tid & 63;
    const int d4    = lane << 2;

    const float* __restrict__ rb = r + (size_t)b * N_ * C_;
    const float* __restrict__ vp = v + (size_t)b * N_ * D_;
    const float scale = 1.0f / (float)N_;
    float* __restrict__ ob = out + (size_t)b * 17 * D_;

    float4 acc[16];
#pragma unroll
    for (int c = 0; c < 16; ++c) acc[c] = make_float4(0.f, 0.f, 0.f, 0.f);

    const int base = chunk * ROWS + wave * RPW;   // 16 consecutive rows

    // group g covers rows base+4g .. base+4g+3
    // r: lane L holds r[base+4g + L/16][L%16]  (one contiguous 64-float load)
    const float* __restrict__ rptr = rb + (size_t)base * C_ + lane;
    const float* __restrict__ vptr = vp + (size_t)base * D_ + d4;

    float  rv;
    float4 v0, v1, v2, v3;
    float  rv_n;
    float4 n0, n1, n2, n3;

#define LOADG(off, RV, A, Bq, Cq, Dq)                                   \
    {                                                                   \
        RV = rptr[(size_t)(off) * C_];                                  \
        const float* _vn = vptr + (size_t)(off) * D_;                   \
        A  = *(const float4*)(_vn + 0 * D_);                            \
        Bq = *(const float4*)(_vn + 1 * D_);                            \
        Cq = *(const float4*)(_vn + 2 * D_);                            \
        Dq = *(const float4*)(_vn + 3 * D_);                            \
    }

#define ACCROW(VV, MASK)                                                \
    {                                                                   \
        const unsigned _m = (MASK);                                     \
        _Pragma("unroll")                                               \
        for (int c = 0; c < 16; ++c) {                                  \
            const float m = (_m & (1u << c)) ? 1.0f : 0.0f;             \
            acc[c].x += (VV).x * m;                                     \
            acc[c].y += (VV).y * m;                                     \
            acc[c].z += (VV).z * m;                                     \
            acc[c].w += (VV).w * m;                                     \
        }                                                               \
        if (_m == 0u) { /* all-below row: prob 0.5^16, rare atomic */   \
            atomicAdd(&ob[16 * D_ + d4 + 0], (VV).x * scale);           \
            atomicAdd(&ob[16 * D_ + d4 + 1], (VV).y * scale);           \
            atomicAdd(&ob[16 * D_ + d4 + 2], (VV).z * scale);           \
            atomicAdd(&ob[16 * D_ + d4 + 3], (VV).w * scale);           \
        }                                                               \
    }

    LOADG(0, rv, v0, v1, v2, v3);

#pragma unroll
    for (int g = 0; g < NG; ++g) {
        if (g + 1 < NG) LOADG((g + 1) * 4, rv_n, n0, n1, n2, n3);

        const unsigned long long bal = __ballot(rv >= 0.5f);
        ACCROW(v0, (unsigned)(bal       ) & 0xFFFFu);
        ACCROW(v1, (unsigned)(bal >> 16 ) & 0xFFFFu);
        ACCROW(v2, (unsigned)(bal >> 32 ) & 0xFFFFu);
        ACCROW(v3, (unsigned)(bal >> 48 ) & 0xFFFFu);

        if (g + 1 < NG) { rv = rv_n; v0 = n0; v1 = n1; v2 = n2; v3 = n3; }
    }

    // ---- cross-wave reduction in LDS (wave0 stores, waves 1..3 accumulate)
    __shared__ float4 lds4[16 * 64];    // 16 KiB
    if (wave == 0) {
#pragma unroll
        for (int c = 0; c < 16; ++c) lds4[c * 64 + lane] = acc[c];
    }
    __syncthreads();
    for (int w = 1; w < 4; ++w) {
        if (wave == w) {
#pragma unroll
            for (int c = 0; c < 16; ++c) {
                float4 t = lds4[c * 64 + lane];
                t.x += acc[c].x; t.y += acc[c].y;
                t.z += acc[c].z; t.w += acc[c].w;
                lds4[c * 64 + lane] = t;
            }
        }
        __syncthreads();
    }

    // ---- one coalesced atomicAdd stream per block (64 contributors/address)
    const float* lf = (const float*)lds4;
#pragma unroll
    for (int c = 0; c < 16; ++c) {
        atomicAdd(&ob[c * D_ + tid], lf[c * 256 + tid] * scale);
    }
}

extern "C" void kernel_launch(void* const* d_in, const int* in_sizes, int n_in,
                              void* d_out, int out_size, void* d_ws, size_t ws_size,
                              hipStream_t stream) {
    const float* r = (const float*)d_in[0];   // (B,N,C) fp32
    const float* v = (const float*)d_in[1];   // (B,N,D) fp32
    float* out = (float*)d_out;               // (B,C+1,D) fp32

    // harness re-poisons d_out to 0xAA before every timed launch
    hipMemsetAsync(out, 0, (size_t)out_size * sizeof(float), stream);

    dim3 grid(B_ * NSPLIT);
    tensor_fusion_kernel<<<grid, 256, 0, stream>>>(r, v, out);
}